// Round 5
// baseline (214.198 us; speedup 1.0000x reference)
//
#include <hip/hip_runtime.h>
#include <stdint.h>

// Problem: x (32,128,8192) f32, weight (128,128,1,2) f32
// out[b,o,p] = sum_{c,k} x[b,c,2p+k] * w[o,c,k] / sqrt(128),  out (32,128,4096) f32
// GEMM: M=(b,p)=131072, N=o=128, K=(c,k)=256. Memory-bound with bf16 MFMA.
//
// R7 = R2 (session argmin, 212.4/212.8 us) with ONE change: the K-loop issue
// order is inverted so the A prefetch is always the YOUNGEST vmcnt entry.
//   R2 order:  pack A(kc) -> issue A(kc+1) -> issue B(kc) -> MFMA(waits B)
//              => waiting on B drains A(kc+1) too (in-order vmcnt), so the
//                 prefetch covers only ~100cy of the ~900cy HBM latency.
//   R7 order:  issue B1,B2 -> pack A(kc)        [waits oldest A, leaves B]
//              -> MFMA th0  [waits B1, leaves B2]
//              -> issue A(kc+1)                 [youngest; survives all waits]
//              -> MFMA th1  [waits B2, leaves A]
//   A(kc+1) now gets th1 (~390cy) + next iter's B-issue+pack (~150cy) of
//   cover; residual ~350cy is coverable by 4-wave TLP. A-prefetch sits after
//   th0 so abuf is dead during th0 -> peak liveness ~120 VGPR, no spill under
//   launch_bounds(256,4). Zero new registers/instructions; numerics identical.
// (R3/R4/R5 attacked the same drain via LDS-B / distance-2 but bundled
//  512-thread blocks + prologues that cost more than the stall; all >= 217.)

typedef __attribute__((ext_vector_type(8))) short bf16x8;   // 8 bf16 = 4 VGPRs
typedef __attribute__((ext_vector_type(4))) float f32x4;    // MFMA C/D

#define CIN  128
#define DLEN 8192
#define PLEN 4096
#define COUT 128

__device__ inline unsigned short f2bf(float f) {
    unsigned u = __builtin_bit_cast(unsigned, f);
    unsigned r = u + 0x7FFFu + ((u >> 16) & 1u);
    return (unsigned short)(r >> 16);
}

// pack two fp32 -> bf16x2 (RTNE), lo = a, hi = b
__device__ inline unsigned pack_bf(float a, float b) {
    unsigned ua = __builtin_bit_cast(unsigned, a);
    unsigned ub = __builtin_bit_cast(unsigned, b);
    unsigned ra = ua + 0x7FFFu + ((ua >> 16) & 1u);
    unsigned rb = ub + 0x7FFFu + ((ub >> 16) & 1u);
    return (ra >> 16) | (rb & 0xFFFF0000u);
}

// Convert weight (o,c,1,k) f32 -> bf16 in B-fragment-major layout, scale folded in.
// W flat index = o*256 + (c*2+k) = o*256 + kk.  WB bf16 index = (kk>>3)*1024 + o*8 + (kk&7).
__global__ __launch_bounds__(256) void convert_w(const float* __restrict__ w,
                                                 unsigned short* __restrict__ wb) {
    int t  = blockIdx.x * 256 + threadIdx.x;   // 0..16383
    int o  = t >> 7;                           // 0..127
    int k0 = (t & 127) * 2;                    // even k index 0..254
    const float scale = 0.088388347648318447f; // 1/sqrt(128)
    float2 f = *(const float2*)(w + o * 256 + k0);
    unsigned v = (unsigned)f2bf(f.x * scale) | ((unsigned)f2bf(f.y * scale) << 16);
    int idx = (k0 >> 3) * 1024 + o * 8 + (k0 & 7);
    *(unsigned*)(wb + idx) = v;
}

// One block = 4 waves = 256 threads, covers 128 positions of one batch, all 128
// outputs, K=256. Each wave: 32 consecutive positions, interleaved across two
// 16x16 M-tiles (tile0 = even offsets, tile1 = odd), so each A row load is one
// float4 covering both tiles. No LDS, no barriers.
__global__ __launch_bounds__(256, 4) void conv_mfma(const float* __restrict__ x,
                                                    const unsigned short* __restrict__ wb,
                                                    float* __restrict__ out) {
    int tile = blockIdx.x;            // 0..1023
    int b    = tile >> 5;
    int pt   = (tile & 31) * 128;
    int lane = threadIdx.x & 63;
    int w    = threadIdx.x >> 6;      // wave 0..3
    int quad = lane >> 4;
    int l16  = lane & 15;
    int pbase = pt + w * 32;          // wave's 32-position strip

    // A lane base: row c = quad*4 (+jj, +16*kc), elem 2*pbase + 4*l16
    const float* xl = x + (size_t)b * ((size_t)CIN * DLEN)
                        + (size_t)(quad * 4) * DLEN + 2 * pbase + 4 * l16;
    const uint32_t* bb = (const uint32_t*)wb + quad * 512 + l16 * 4;

    f32x4 acc[2][8];
#pragma unroll
    for (int mt = 0; mt < 2; ++mt)
#pragma unroll
        for (int t = 0; t < 8; ++t)
            acc[mt][t] = (f32x4)(0.0f);

    // preload kc=0 A
    float4 abuf[4];
#pragma unroll
    for (int jj = 0; jj < 4; ++jj)
        abuf[jj] = *(const float4*)(xl + (size_t)jj * DLEN);

#pragma unroll 1
    for (int kc = 0; kc < 8; ++kc) {
        // 1) issue ALL B loads for this kc first. Queue: [A(kc), B1, B2].
        //    Later waits on B never touch anything younger than themselves.
        const uint32_t* bk = bb + kc * 2048;
        union { bf16x8 v; uint4 u; } bfr[8];
#pragma unroll
        for (int t = 0; t < 8; ++t)
            bfr[t].u = *(const uint4*)(bk + t * 64);

        // 2) pack current A (waits on oldest = A(kc) only; B1/B2 stay in flight)
        union { bf16x8 v; unsigned uu[4]; } afr0, afr1;
#pragma unroll
        for (int jj = 0; jj < 4; ++jj) {
            afr0.uu[jj] = pack_bf(abuf[jj].x, abuf[jj].y);
            afr1.uu[jj] = pack_bf(abuf[jj].z, abuf[jj].w);
        }

        // 3) MFMA half 1 (waits B1 -> leaves B2 in flight; abuf dead here,
        //    keeping peak liveness under the 128-VGPR / 4-wave budget)
#pragma unroll
        for (int t = 0; t < 4; ++t) {
            acc[0][t] = __builtin_amdgcn_mfma_f32_16x16x32_bf16(afr0.v, bfr[t].v, acc[0][t], 0, 0, 0);
            acc[1][t] = __builtin_amdgcn_mfma_f32_16x16x32_bf16(afr1.v, bfr[t].v, acc[1][t], 0, 0, 0);
        }

        // 4) prefetch next A — issued AFTER all B, so it is the youngest
        //    queue entry and survives every B wait; covered by th1 + next pack
        if (kc < 7) {
            const float* nx = xl + (size_t)((kc + 1) * 16) * DLEN;
#pragma unroll
            for (int jj = 0; jj < 4; ++jj)
                abuf[jj] = *(const float4*)(nx + (size_t)jj * DLEN);
        }

        // 5) MFMA half 2 (waits B2 -> leaves A(kc+1) in flight)
#pragma unroll
        for (int t = 4; t < 8; ++t) {
            acc[0][t] = __builtin_amdgcn_mfma_f32_16x16x32_bf16(afr0.v, bfr[t].v, acc[0][t], 0, 0, 0);
            acc[1][t] = __builtin_amdgcn_mfma_f32_16x16x32_bf16(afr1.v, bfr[t].v, acc[1][t], 0, 0, 0);
        }
    }

    // Epilogue: C/D row = quad*4 + reg. tile0 reg r -> p = pbase+8q+2r,
    // tile1 -> +1. Interleave regs -> 8 consecutive positions per t.
    float* ob = out + (size_t)b * ((size_t)COUT * PLEN) + pbase + quad * 8;
#pragma unroll
    for (int t = 0; t < 8; ++t) {
        int o = t * 16 + l16;
        float* orow = ob + (size_t)o * PLEN;
        f32x4 v0 = { acc[0][t][0], acc[1][t][0], acc[0][t][1], acc[1][t][1] };
        f32x4 v1 = { acc[0][t][2], acc[1][t][2], acc[0][t][3], acc[1][t][3] };
        *(f32x4*)(orow)     = v0;
        *(f32x4*)(orow + 4) = v1;
    }
}

extern "C" void kernel_launch(void* const* d_in, const int* in_sizes, int n_in,
                              void* d_out, int out_size, void* d_ws, size_t ws_size,
                              hipStream_t stream) {
    const float* x = (const float*)d_in[0];
    const float* w = (const float*)d_in[1];
    float* out = (float*)d_out;
    unsigned short* wb = (unsigned short*)d_ws;  // 64 KB of bf16 weights

    convert_w<<<64, 256, 0, stream>>>(w, wb);
    conv_mfma<<<1024, 256, 0, stream>>>(x, wb, out);
}